// Round 6
// baseline (398.388 us; speedup 1.0000x reference)
//
#include <hip/hip_runtime.h>

#define HH 512
#define WW 512
#define PLANES 96          // 32 * 3
#define RSTRIP 128         // output rows per block; halo overhead 7.8%
#define NPIX 25165824.0f   // 32*3*512*512

// Gaussian weights (sigma=1.5, K=11), symmetric; these exact constants gave absmax 0.0
#define G0 0.2660117f
#define G1 0.2130056f
#define G2 0.1093607f
#define G3 0.0360008f
#define G4 0.0075988f
#define G5 0.0010284f

#define C1F 1e-4f
#define C2F 9e-4f

struct F4 { float s0, s1, s2, s3; };

// 11-deep named-scalar history (SSA values; no alloca possible)
#define DECL_HIST(Z) float Z##0=0.f,Z##1=0.f,Z##2=0.f,Z##3=0.f,Z##4=0.f,Z##5=0.f,\
                           Z##6=0.f,Z##7=0.f,Z##8=0.f,Z##9=0.f,Z##10=0.f
#define SHIFT_HIST(Z) do{Z##0=Z##1;Z##1=Z##2;Z##2=Z##3;Z##3=Z##4;Z##4=Z##5;\
                         Z##5=Z##6;Z##6=Z##7;Z##7=Z##8;Z##8=Z##9;Z##9=Z##10;}while(0)
#define VCONV(Z) fmaf(G5, Z##0+Z##10, fmaf(G4, Z##1+Z##9, fmaf(G3, Z##2+Z##8,\
                 fmaf(G2, Z##3+Z##7, fmaf(G1, Z##4+Z##6, G0*Z##5)))))

// Fill the 6 pending F4s from row pointers R1/R2 (at column c, offset -5..+6)
#define LOAD_ROW(R1, R2)                                                        \
    do {                                                                        \
        if (!edge) {                                                            \
            __builtin_memcpy(&pxa, (R1) - 5, 16);                               \
            __builtin_memcpy(&pxb, (R1) - 1, 16);                               \
            __builtin_memcpy(&pxc, (R1) + 3, 16);                               \
            __builtin_memcpy(&pya, (R2) - 5, 16);                               \
            __builtin_memcpy(&pyb, (R2) - 1, 16);                               \
            __builtin_memcpy(&pyc, (R2) + 3, 16);                               \
        } else {                                                                \
            ET(pxa.s0, pya.s0, 0)  ET(pxa.s1, pya.s1, 1)                        \
            ET(pxa.s2, pya.s2, 2)  ET(pxa.s3, pya.s3, 3)                        \
            ET(pxb.s0, pyb.s0, 4)  ET(pxb.s1, pyb.s1, 5)                        \
            ET(pxb.s2, pyb.s2, 6)  ET(pxb.s3, pyb.s3, 7)                        \
            ET(pxc.s0, pyc.s0, 8)  ET(pxc.s1, pyc.s1, 9)                        \
            ET(pxc.s2, pyc.s2, 10) pxc.s3 = 0.f; pyc.s3 = 0.f;                  \
        }                                                                       \
    } while (0)
#define ET(FX, FY, K) { int cc = c + (K) - 5; bool ok = (unsigned)cc < (unsigned)WW; \
                        FX = ok ? (R1_)[(K) - 5] : 0.f; FY = ok ? (R2_)[(K) - 5] : 0.f; }

#define ZERO_PEND do { pxa = {0,0,0,0}; pxb = {0,0,0,0}; pxc = {0,0,0,0};       \
                       pya = {0,0,0,0}; pyb = {0,0,0,0}; pyc = {0,0,0,0}; } while (0)

// Rounds 1-5 invariant: VALUBusy ~35%, ~2900 cyc per 3-wave SIMD iteration
// slot regardless of VGPR budget (40->68) or source shape => each iteration's
// 6 row-loads are issued and consumed in the SAME iteration, exposing ~900 cyc
// of first-touch HBM latency that 3 waves/SIMD can't hide. This version
// software-pipelines one iteration ahead: consume pending regs (row t), issue
// loads for row t+1, THEN compute -> issue-to-use distance ~3x370 cyc > 900.
__global__ __launch_bounds__(256) __attribute__((amdgpu_waves_per_eu(3, 3)))
void ssim_main(const float* __restrict__ img1,
               const float* __restrict__ img2,
               float* __restrict__ acc) {
    const int c  = blockIdx.x * 256 + threadIdx.x;   // column (0..511)
    const int r0 = blockIdx.y * RSTRIP;              // first output row of strip
    const int p  = blockIdx.z;                       // plane (b*3+ch)
    const size_t pb = (size_t)p * (HH * WW);
    const bool edge = (c < 5) || (c > WW - 7);

    // pointer to NEXT row to prefetch (starts at row r0-4; preload covers r0-5)
    const float* rn1 = img1 + pb + (ptrdiff_t)(r0 - 4) * WW + c;
    const float* rn2 = img2 + pb + (ptrdiff_t)(r0 - 4) * WW + c;

    // histories: A=conv(u), B=conv(v), P=conv(u^2), Q=conv(v^2); u=x+y, v=x-y
    DECL_HIST(A); DECL_HIST(B); DECL_HIST(P); DECL_HIST(Q);

    // pending (prefetched) row registers
    F4 pxa, pxb, pxc, pya, pyb, pyc;

    // preload row r0-5 (zero if outside image; happens only for blockIdx.y==0)
    {
        const int t0 = r0 - 5;
        const float* R1_ = rn1 - WW;
        const float* R2_ = rn2 - WW;
        if ((unsigned)t0 < (unsigned)HH) LOAD_ROW(R1_, R2_);
        else                             ZERO_PEND;
    }

    float lsum = 0.f;

#pragma unroll 2
    for (int t = r0 - 5; t <= r0 + RSTRIP + 4; ++t, rn1 += WW, rn2 += WW) {
        // ---- consume pending (row t); pure register renames
        const float X0=pxa.s0, X1=pxa.s1, X2=pxa.s2, X3=pxa.s3,
                    X4=pxb.s0, X5=pxb.s1, X6=pxb.s2, X7=pxb.s3,
                    X8=pxc.s0, X9=pxc.s1, X10=pxc.s2;
        const float Y0=pya.s0, Y1=pya.s1, Y2=pya.s2, Y3=pya.s3,
                    Y4=pyb.s0, Y5=pyb.s1, Y6=pyb.s2, Y7=pyb.s3,
                    Y8=pyc.s0, Y9=pyc.s1, Y10=pyc.s2;

        // ---- issue prefetch for row t+1 (no dependency on this iter's math)
        {
            const int tn = t + 1;
            const float* R1_ = rn1;
            const float* R2_ = rn2;
            if ((unsigned)tn < (unsigned)HH && t < r0 + RSTRIP + 4) LOAD_ROW(R1_, R2_);
            else                                                    ZERO_PEND;
        }

        // ---- compute row t (zero rows flow through as zeros; no branch needed)
        SHIFT_HIST(A); SHIFT_HIST(B); SHIFT_HIST(P); SHIFT_HIST(Q);

        const float U0=X0+Y0, V0=X0-Y0;
        const float U1=X1+Y1, V1=X1-Y1;
        const float U2=X2+Y2, V2=X2-Y2;
        const float U3=X3+Y3, V3=X3-Y3;
        const float U4=X4+Y4, V4=X4-Y4;
        const float U5=X5+Y5, V5=X5-Y5;
        const float U6=X6+Y6, V6=X6-Y6;
        const float U7=X7+Y7, V7=X7-Y7;
        const float U8=X8+Y8, V8=X8-Y8;
        const float U9=X9+Y9, V9=X9-Y9;
        const float U10=X10+Y10, V10=X10-Y10;

        float nA = G0*U5,      nB = G0*V5;
        float nP = G0*(U5*U5), nQ = G0*(V5*V5);
        nA = fmaf(G1, U4+U6,  nA); nP = fmaf(G1, fmaf(U4,U4,U6*U6),   nP);
        nB = fmaf(G1, V4+V6,  nB); nQ = fmaf(G1, fmaf(V4,V4,V6*V6),   nQ);
        nA = fmaf(G2, U3+U7,  nA); nP = fmaf(G2, fmaf(U3,U3,U7*U7),   nP);
        nB = fmaf(G2, V3+V7,  nB); nQ = fmaf(G2, fmaf(V3,V3,V7*V7),   nQ);
        nA = fmaf(G3, U2+U8,  nA); nP = fmaf(G3, fmaf(U2,U2,U8*U8),   nP);
        nB = fmaf(G3, V2+V8,  nB); nQ = fmaf(G3, fmaf(V2,V2,V8*V8),   nQ);
        nA = fmaf(G4, U1+U9,  nA); nP = fmaf(G4, fmaf(U1,U1,U9*U9),   nP);
        nB = fmaf(G4, V1+V9,  nB); nQ = fmaf(G4, fmaf(V1,V1,V9*V9),   nQ);
        nA = fmaf(G5, U0+U10, nA); nP = fmaf(G5, fmaf(U0,U0,U10*U10), nP);
        nB = fmaf(G5, V0+V10, nB); nQ = fmaf(G5, fmaf(V0,V0,V10*V10), nQ);
        A10 = nA; B10 = nB; P10 = nP; Q10 = nQ;

        const int s = t - 5 - r0;                    // output row within strip
        if ((unsigned)s < (unsigned)RSTRIP) {        // uniform; first 10 iters warm up
            const float mu_u = VCONV(A);
            const float mu_v = VCONV(B);
            const float cu2  = VCONV(P);
            const float cv2  = VCONV(Q);
            const float a = mu_u * mu_u;
            const float b = mu_v * mu_v;
            const float musq = 0.5f  * (a + b);      // mu1^2 + mu2^2
            const float mu12 = 0.25f * (a - b);      // mu1 * mu2
            const float csq  = 0.5f  * (cu2 + cv2);  // conv(x^2) + conv(y^2)
            const float cxy  = 0.25f * (cu2 - cv2);  // conv(x*y)
            const float ssum = csq - musq;           // sigma1^2 + sigma2^2
            const float s12  = cxy - mu12;           // sigma12
            const float num = fmaf(2.f, mu12, C1F) * fmaf(2.f, s12, C2F);
            const float den = (musq + C1F) * (ssum + C2F);
            lsum += num * __builtin_amdgcn_rcpf(den);
        }
    }

    // reduction: wave shfl -> LDS -> one atomic per block
#pragma unroll
    for (int off = 32; off > 0; off >>= 1)
        lsum += __shfl_down(lsum, off, 64);
    __shared__ float ws4[4];
    const int lane = threadIdx.x & 63;
    const int wv   = threadIdx.x >> 6;
    if (lane == 0) ws4[wv] = lsum;
    __syncthreads();
    if (threadIdx.x == 0)
        atomicAdd(acc, ws4[0] + ws4[1] + ws4[2] + ws4[3]);
}

__global__ void ssim_zero(float* acc) { acc[0] = 0.f; }

__global__ void ssim_finalize(const float* __restrict__ acc, float* __restrict__ out) {
    out[0] = 1.f - acc[0] * (1.f / NPIX);
}

extern "C" void kernel_launch(void* const* d_in, const int* in_sizes, int n_in,
                              void* d_out, int out_size, void* d_ws, size_t ws_size,
                              hipStream_t stream) {
    const float* img1 = (const float*)d_in[0];
    const float* img2 = (const float*)d_in[1];
    float* out = (float*)d_out;
    float* acc = (float*)d_ws;

    ssim_zero<<<1, 1, 0, stream>>>(acc);
    dim3 grid(WW / 256, HH / RSTRIP, PLANES);  // (2, 4, 96) = 768 blocks = 3/CU
    ssim_main<<<grid, 256, 0, stream>>>(img1, img2, acc);
    ssim_finalize<<<1, 1, 0, stream>>>(acc, out);
}

// Round 7
// 354.522 us; speedup vs baseline: 1.1237x; 1.1237x over previous
//
#include <hip/hip_runtime.h>

#define HH 512
#define WW 512
#define PLANES 96          // 32 * 3
#define RSTRIP 64          // output rows per block; grid = 1536 blocks = 6/CU (TLP!)
#define NPIX 25165824.0f   // 32*3*512*512

// Gaussian weights (sigma=1.5, K=11), symmetric; these exact constants gave absmax 0.0
#define G0 0.2660117f
#define G1 0.2130056f
#define G2 0.1093607f
#define G3 0.0360008f
#define G4 0.0075988f
#define G5 0.0010284f

#define C1F 1e-4f
#define C2F 9e-4f

struct F4 { float s0, s1, s2, s3; };

// 11-deep named-scalar history (SSA values; no alloca possible)
#define DECL_HIST(Z) float Z##0=0.f,Z##1=0.f,Z##2=0.f,Z##3=0.f,Z##4=0.f,Z##5=0.f,\
                           Z##6=0.f,Z##7=0.f,Z##8=0.f,Z##9=0.f,Z##10=0.f
#define SHIFT_HIST(Z) do{Z##0=Z##1;Z##1=Z##2;Z##2=Z##3;Z##3=Z##4;Z##4=Z##5;\
                         Z##5=Z##6;Z##6=Z##7;Z##7=Z##8;Z##8=Z##9;Z##9=Z##10;}while(0)
#define VCONV(Z) fmaf(G5, Z##0+Z##10, fmaf(G4, Z##1+Z##9, fmaf(G3, Z##2+Z##8,\
                 fmaf(G2, Z##3+Z##7, fmaf(G1, Z##4+Z##6, G0*Z##5)))))

// Rounds 0-6 post-mortem: occupancy was grid/attr-pinned at 12 waves/CU the
// whole time. Per-CU iteration slot = ~4560 cyc = 3 x (900 HBM latency + 620
// VALU): 3 waves/SIMD cannot overlap their first-touch load stalls, and every
// source-level scheduling trick (launch_bounds, waves_per_eu(3,3), named
// scalars, software prefetch) failed to change the compiler's tight load->use
// chains. Fix is TLP, not scheduling: RSTRIP 128->64 doubles the grid to
// 6 blocks/CU (24 waves), waves_per_eu(6,6) sets the VGPR budget ~85 (round-5
// body used 68). 5 other waves x 620 cyc VALU >> 900 cyc latency.
__global__ __launch_bounds__(256) __attribute__((amdgpu_waves_per_eu(6, 6)))
void ssim_main(const float* __restrict__ img1,
               const float* __restrict__ img2,
               float* __restrict__ acc) {
    const int c  = blockIdx.x * 256 + threadIdx.x;   // column (0..511)
    const int r0 = blockIdx.y * RSTRIP;              // first output row of strip
    const int p  = blockIdx.z;                       // plane (b*3+ch)
    const size_t pb = (size_t)p * (HH * WW);
    const bool edge = (c < 5) || (c > WW - 7);

    // row pointers at (t, c); advanced by WW per iteration (deref is guarded)
    const float* rp1 = img1 + pb + (ptrdiff_t)(r0 - 5) * WW + c;
    const float* rp2 = img2 + pb + (ptrdiff_t)(r0 - 5) * WW + c;

    // histories: A=conv(u), B=conv(v), P=conv(u^2), Q=conv(v^2); u=x+y, v=x-y
    DECL_HIST(A); DECL_HIST(B); DECL_HIST(P); DECL_HIST(Q);

    float lsum = 0.f;

#pragma unroll 2
    for (int t = r0 - 5; t <= r0 + RSTRIP + 4; ++t, rp1 += WW, rp2 += WW) {
        SHIFT_HIST(A); SHIFT_HIST(B); SHIFT_HIST(P); SHIFT_HIST(Q);

        float nA = 0.f, nB = 0.f, nP = 0.f, nQ = 0.f;
        if ((unsigned)t < (unsigned)HH) {            // uniform; rows outside are zero-pad
            float X0,X1,X2,X3,X4,X5,X6,X7,X8,X9,X10;
            float Y0,Y1,Y2,Y3,Y4,Y5,Y6,Y7,Y8,Y9,Y10;
            if (!edge) {
                F4 xa, xb, xc, ya, yb, yc;
                __builtin_memcpy(&xa, rp1 - 5, 16);
                __builtin_memcpy(&xb, rp1 - 1, 16);
                __builtin_memcpy(&xc, rp1 + 3, 16);
                __builtin_memcpy(&ya, rp2 - 5, 16);
                __builtin_memcpy(&yb, rp2 - 1, 16);
                __builtin_memcpy(&yc, rp2 + 3, 16);
                X0=xa.s0; X1=xa.s1; X2=xa.s2; X3=xa.s3;
                X4=xb.s0; X5=xb.s1; X6=xb.s2; X7=xb.s3;
                X8=xc.s0; X9=xc.s1; X10=xc.s2;
                Y0=ya.s0; Y1=ya.s1; Y2=ya.s2; Y3=ya.s3;
                Y4=yb.s0; Y5=yb.s1; Y6=yb.s2; Y7=yb.s3;
                Y8=yc.s0; Y9=yc.s1; Y10=yc.s2;
            } else {
#define EDGE_TAP(K) { int cc = c + (K) - 5; bool ok = (unsigned)cc < (unsigned)WW; \
                      X##K = ok ? rp1[(K) - 5] : 0.f; Y##K = ok ? rp2[(K) - 5] : 0.f; }
                EDGE_TAP(0) EDGE_TAP(1) EDGE_TAP(2) EDGE_TAP(3) EDGE_TAP(4)
                EDGE_TAP(5) EDGE_TAP(6) EDGE_TAP(7) EDGE_TAP(8) EDGE_TAP(9) EDGE_TAP(10)
#undef EDGE_TAP
            }
            const float U0=X0+Y0, V0=X0-Y0;
            const float U1=X1+Y1, V1=X1-Y1;
            const float U2=X2+Y2, V2=X2-Y2;
            const float U3=X3+Y3, V3=X3-Y3;
            const float U4=X4+Y4, V4=X4-Y4;
            const float U5=X5+Y5, V5=X5-Y5;
            const float U6=X6+Y6, V6=X6-Y6;
            const float U7=X7+Y7, V7=X7-Y7;
            const float U8=X8+Y8, V8=X8-Y8;
            const float U9=X9+Y9, V9=X9-Y9;
            const float U10=X10+Y10, V10=X10-Y10;

            nA = G0*U5;        nB = G0*V5;
            nP = G0*(U5*U5);   nQ = G0*(V5*V5);
            nA = fmaf(G1, U4+U6,  nA); nP = fmaf(G1, fmaf(U4,U4,U6*U6),   nP);
            nB = fmaf(G1, V4+V6,  nB); nQ = fmaf(G1, fmaf(V4,V4,V6*V6),   nQ);
            nA = fmaf(G2, U3+U7,  nA); nP = fmaf(G2, fmaf(U3,U3,U7*U7),   nP);
            nB = fmaf(G2, V3+V7,  nB); nQ = fmaf(G2, fmaf(V3,V3,V7*V7),   nQ);
            nA = fmaf(G3, U2+U8,  nA); nP = fmaf(G3, fmaf(U2,U2,U8*U8),   nP);
            nB = fmaf(G3, V2+V8,  nB); nQ = fmaf(G3, fmaf(V2,V2,V8*V8),   nQ);
            nA = fmaf(G4, U1+U9,  nA); nP = fmaf(G4, fmaf(U1,U1,U9*U9),   nP);
            nB = fmaf(G4, V1+V9,  nB); nQ = fmaf(G4, fmaf(V1,V1,V9*V9),   nQ);
            nA = fmaf(G5, U0+U10, nA); nP = fmaf(G5, fmaf(U0,U0,U10*U10), nP);
            nB = fmaf(G5, V0+V10, nB); nQ = fmaf(G5, fmaf(V0,V0,V10*V10), nQ);
        }
        A10 = nA; B10 = nB; P10 = nP; Q10 = nQ;

        const int s = t - 5 - r0;                    // output row within strip
        if ((unsigned)s < (unsigned)RSTRIP) {        // uniform; first 10 iters warm up
            const float mu_u = VCONV(A);
            const float mu_v = VCONV(B);
            const float cu2  = VCONV(P);
            const float cv2  = VCONV(Q);
            const float a = mu_u * mu_u;
            const float b = mu_v * mu_v;
            const float musq = 0.5f  * (a + b);      // mu1^2 + mu2^2
            const float mu12 = 0.25f * (a - b);      // mu1 * mu2
            const float csq  = 0.5f  * (cu2 + cv2);  // conv(x^2) + conv(y^2)
            const float cxy  = 0.25f * (cu2 - cv2);  // conv(x*y)
            const float ssum = csq - musq;           // sigma1^2 + sigma2^2
            const float s12  = cxy - mu12;           // sigma12
            const float num = fmaf(2.f, mu12, C1F) * fmaf(2.f, s12, C2F);
            const float den = (musq + C1F) * (ssum + C2F);
            lsum += num * __builtin_amdgcn_rcpf(den);
        }
    }

    // reduction: wave shfl -> LDS -> one atomic per block
#pragma unroll
    for (int off = 32; off > 0; off >>= 1)
        lsum += __shfl_down(lsum, off, 64);
    __shared__ float ws4[4];
    const int lane = threadIdx.x & 63;
    const int wv   = threadIdx.x >> 6;
    if (lane == 0) ws4[wv] = lsum;
    __syncthreads();
    if (threadIdx.x == 0)
        atomicAdd(acc, ws4[0] + ws4[1] + ws4[2] + ws4[3]);
}

__global__ void ssim_zero(float* acc) { acc[0] = 0.f; }

__global__ void ssim_finalize(const float* __restrict__ acc, float* __restrict__ out) {
    out[0] = 1.f - acc[0] * (1.f / NPIX);
}

extern "C" void kernel_launch(void* const* d_in, const int* in_sizes, int n_in,
                              void* d_out, int out_size, void* d_ws, size_t ws_size,
                              hipStream_t stream) {
    const float* img1 = (const float*)d_in[0];
    const float* img2 = (const float*)d_in[1];
    float* out = (float*)d_out;
    float* acc = (float*)d_ws;

    ssim_zero<<<1, 1, 0, stream>>>(acc);
    dim3 grid(WW / 256, HH / RSTRIP, PLANES);  // (2, 8, 96) = 1536 blocks = 6/CU
    ssim_main<<<grid, 256, 0, stream>>>(img1, img2, acc);
    ssim_finalize<<<1, 1, 0, stream>>>(acc, out);
}